// Round 1
// baseline (773.167 us; speedup 1.0000x reference)
//
#include <hip/hip_runtime.h>

#define EPSV 1e-5f

// ---------------------------------------------------------------------------
// conv1: ctrl [8,128,128,128] -> h [8,50,128,128], fused bias+ReLU+BN
// grid (4,4,16): z = b*2 + cohalf ; block 256
// tile 32x32 spatial, 25 out-ch per block, thread = 4 pixels (y stride 8) x 25 co
// ---------------------------------------------------------------------------
__global__ __launch_bounds__(256) void conv1_kernel(
    const float* __restrict__ x, const float* __restrict__ w1,
    const float* __restrict__ b1, const float* __restrict__ gamma,
    const float* __restrict__ beta, const float* __restrict__ mean,
    const float* __restrict__ var, float* __restrict__ h)
{
    __shared__ float in_s[8][34][34];   // 37.0 KB
    __shared__ float w_s[8][9][28];     // 8.1 KB (co padded 25->28 for b128)
    const int tid = threadIdx.x;
    const int x0 = blockIdx.x * 32, y0 = blockIdx.y * 32;
    const int b = blockIdx.z >> 1;
    const int cobase = (blockIdx.z & 1) * 25;
    const int tx = tid & 31, ty = tid >> 5;

    float acc[25][4];
#pragma unroll
    for (int co = 0; co < 25; co++)
#pragma unroll
        for (int p = 0; p < 4; p++) acc[co][p] = 0.f;

    for (int ci0 = 0; ci0 < 128; ci0 += 8) {
        // stage input tile (8 ch x 34 x 34, zero-padded at image edges)
        for (int c = 0; c < 8; c++) {
            for (int j = tid; j < 34 * 34; j += 256) {
                int yy = j / 34, xx = j % 34;
                int gy = y0 + yy - 1, gx = x0 + xx - 1;
                float v = 0.f;
                if (gy >= 0 && gy < 128 && gx >= 0 && gx < 128)
                    v = x[(((size_t)b * 128 + ci0 + c) * 128 + gy) * 128 + gx];
                in_s[c][yy][xx] = v;
            }
        }
        // stage weights: w1[co][ci][tap] -> w_s[ci][tap][co]
        for (int i = tid; i < 8 * 9 * 25; i += 256) {
            int co = i % 25;
            int t2 = i / 25;
            int tap = t2 % 9;
            int c = t2 / 9;
            w_s[c][tap][co] = w1[((size_t)(cobase + co) * 128 + ci0 + c) * 9 + tap];
        }
        __syncthreads();

        for (int c = 0; c < 8; c++) {
#pragma unroll
            for (int tap = 0; tap < 9; tap++) {
                const int dy = tap / 3, dx = tap % 3;
                float v0 = in_s[c][ty + dy][tx + dx];
                float v1 = in_s[c][ty + 8 + dy][tx + dx];
                float v2 = in_s[c][ty + 16 + dy][tx + dx];
                float v3 = in_s[c][ty + 24 + dy][tx + dx];
#pragma unroll
                for (int co = 0; co < 25; co++) {
                    float wv = w_s[c][tap][co];
                    acc[co][0] += v0 * wv;
                    acc[co][1] += v1 * wv;
                    acc[co][2] += v2 * wv;
                    acc[co][3] += v3 * wv;
                }
            }
        }
        __syncthreads();
    }

    // epilogue: bias, ReLU, BN(inference), store
    const int gx = x0 + tx;
#pragma unroll
    for (int co = 0; co < 25; co++) {
        int cog = cobase + co;
        float sc = gamma[cog] * rsqrtf(var[cog] + EPSV);
        float mn = mean[cog], bt = beta[cog], bs = b1[cog];
#pragma unroll
        for (int p = 0; p < 4; p++) {
            int gy = y0 + ty + 8 * p;
            float r = fmaxf(acc[co][p] + bs, 0.f);
            r = (r - mn) * sc + bt;
            h[(((size_t)b * 50 + cog) * 128 + gy) * 128 + gx] = r;
        }
    }
}

// ---------------------------------------------------------------------------
// conv2: h [8,50,128,128] -> cond [8,18,128,128], fused bias
// grid (4,8,8); block 256; tile 32x16, 18 out-ch, thread = 2 pixels x 18 co
// ---------------------------------------------------------------------------
__global__ __launch_bounds__(256) void conv2_kernel(
    const float* __restrict__ hin, const float* __restrict__ w2,
    const float* __restrict__ b2, float* __restrict__ cond)
{
    __shared__ float in_s[10][18][34];  // 24.5 KB
    __shared__ float w_s[10][9][20];    // 7.2 KB (co padded 18->20)
    const int tid = threadIdx.x;
    const int x0 = blockIdx.x * 32, y0 = blockIdx.y * 16;
    const int b = blockIdx.z;
    const int tx = tid & 31, ty = tid >> 5;

    float acc[18][2];
#pragma unroll
    for (int co = 0; co < 18; co++) { acc[co][0] = 0.f; acc[co][1] = 0.f; }

    for (int ci0 = 0; ci0 < 50; ci0 += 10) {
        for (int c = 0; c < 10; c++) {
            for (int j = tid; j < 18 * 34; j += 256) {
                int yy = j / 34, xx = j % 34;
                int gy = y0 + yy - 1, gx = x0 + xx - 1;
                float v = 0.f;
                if (gy >= 0 && gy < 128 && gx >= 0 && gx < 128)
                    v = hin[(((size_t)b * 50 + ci0 + c) * 128 + gy) * 128 + gx];
                in_s[c][yy][xx] = v;
            }
        }
        for (int i = tid; i < 10 * 9 * 18; i += 256) {
            int co = i % 18;
            int t2 = i / 18;
            int tap = t2 % 9;
            int c = t2 / 9;
            w_s[c][tap][co] = w2[((size_t)co * 50 + ci0 + c) * 9 + tap];
        }
        __syncthreads();

        for (int c = 0; c < 10; c++) {
#pragma unroll
            for (int tap = 0; tap < 9; tap++) {
                const int dy = tap / 3, dx = tap % 3;
                float v0 = in_s[c][ty + dy][tx + dx];
                float v1 = in_s[c][ty + 8 + dy][tx + dx];
#pragma unroll
                for (int co = 0; co < 18; co++) {
                    float wv = w_s[c][tap][co];
                    acc[co][0] += v0 * wv;
                    acc[co][1] += v1 * wv;
                }
            }
        }
        __syncthreads();
    }

    const int gx = x0 + tx;
#pragma unroll
    for (int co = 0; co < 18; co++) {
        float bs = b2[co];
#pragma unroll
        for (int p = 0; p < 2; p++) {
            int gy = y0 + ty + 8 * p;
            cond[(((size_t)b * 18 + co) * 128 + gy) * 128 + gx] = acc[co][p] + bs;
        }
    }
}

// ---------------------------------------------------------------------------
// apply: out[b,c,y,x] = sum_k img[b,c,y+(k%3)*4-4, x+(k/3)*4-4] * w[b, (c/3)*9+k, y/4, x/4]
// thread = one aligned float4 (a cell row) x 6 channels. grid 2048 x 256.
// ---------------------------------------------------------------------------
__global__ __launch_bounds__(256) void apply_kernel(
    const float* __restrict__ img, const float* __restrict__ cond,
    float* __restrict__ out)
{
    const int t = blockIdx.x * 256 + threadIdx.x;
    const int x4 = t & 127;         // x/4
    const int y = (t >> 7) & 511;
    const int b = t >> 16;
    const int cy = y >> 2;

    float w[2][9];
#pragma unroll
    for (int g = 0; g < 2; g++)
#pragma unroll
        for (int k = 0; k < 9; k++)
            w[g][k] = cond[(((size_t)b * 18 + g * 9 + k) * 128 + cy) * 128 + x4];

#pragma unroll
    for (int c = 0; c < 6; c++) {
        const int g = c / 3;
        float4 acc = make_float4(0.f, 0.f, 0.f, 0.f);
#pragma unroll
        for (int i = 0; i < 3; i++) {
            int xx = x4 * 4 + i * 4 - 4;
            if (xx < 0 || xx >= 512) continue;
#pragma unroll
            for (int j = 0; j < 3; j++) {
                int yy = y + j * 4 - 4;
                if (yy < 0 || yy >= 512) continue;
                const float4 v = *(const float4*)&img[(((size_t)b * 6 + c) * 512 + yy) * 512 + xx];
                float wv = w[g][i * 3 + j];
                acc.x += v.x * wv;
                acc.y += v.y * wv;
                acc.z += v.z * wv;
                acc.w += v.w * wv;
            }
        }
        *(float4*)&out[(((size_t)b * 6 + c) * 512 + y) * 512 + x4 * 4] = acc;
    }
}

// ---------------------------------------------------------------------------
extern "C" void kernel_launch(void* const* d_in, const int* in_sizes, int n_in,
                              void* d_out, int out_size, void* d_ws, size_t ws_size,
                              hipStream_t stream)
{
    const float* img   = (const float*)d_in[0];
    const float* ctrl  = (const float*)d_in[1];
    const float* w1    = (const float*)d_in[2];
    const float* b1    = (const float*)d_in[3];
    const float* gamma = (const float*)d_in[4];
    const float* beta  = (const float*)d_in[5];
    const float* mean  = (const float*)d_in[6];
    const float* var   = (const float*)d_in[7];
    const float* w2    = (const float*)d_in[8];
    const float* b2    = (const float*)d_in[9];
    float* out = (float*)d_out;

    float* h    = (float*)d_ws;                         // 8*50*128*128 floats = 26.2 MB
    float* cond = h + (size_t)8 * 50 * 128 * 128;       // 8*18*128*128 floats =  9.4 MB

    conv1_kernel<<<dim3(4, 4, 16), 256, 0, stream>>>(ctrl, w1, b1, gamma, beta, mean, var, h);
    conv2_kernel<<<dim3(4, 8, 8), 256, 0, stream>>>(h, w2, b2, cond);
    apply_kernel<<<2048, 256, 0, stream>>>(img, cond, out);
}

// Round 2
// 268.925 us; speedup vs baseline: 2.8750x; 2.8750x over previous
//
#include <hip/hip_runtime.h>

typedef __attribute__((ext_vector_type(8))) short short8;
typedef __attribute__((ext_vector_type(4))) float floatx4;

__device__ __forceinline__ unsigned short f2bf(float f) {
    union { float f; unsigned int u; } v; v.f = f;
    unsigned int r = (v.u + 0x7fffu + ((v.u >> 16) & 1u)) >> 16;
    return (unsigned short)r;
}

// ---------------------------------------------------------------------------
// T: ctrl [8,128,128,128] f32 NCHW -> ctrlT [8,128y,128x,128ci] bf16 NHWC
// grid (2 x-tiles, 2 ci-tiles, b*y=1024); block 256
// ---------------------------------------------------------------------------
__global__ __launch_bounds__(256) void transpose_kernel(
    const float* __restrict__ ctrl, unsigned short* __restrict__ ctrlT)
{
    __shared__ unsigned short tile[64 * 66];
    const int t = threadIdx.x;
    const int x0 = blockIdx.x * 64, ci0 = blockIdx.y * 64;
    const int b = blockIdx.z >> 7, y = blockIdx.z & 127;
#pragma unroll
    for (int it = 0; it < 4; it++) {
        int ci_l = it * 16 + (t >> 4);
        int x_l = (t & 15) * 4;
        const float4 v = *(const float4*)&ctrl[(((size_t)b * 128 + ci0 + ci_l) * 128 + y) * 128 + x0 + x_l];
        tile[(x_l + 0) * 66 + ci_l] = f2bf(v.x);
        tile[(x_l + 1) * 66 + ci_l] = f2bf(v.y);
        tile[(x_l + 2) * 66 + ci_l] = f2bf(v.z);
        tile[(x_l + 3) * 66 + ci_l] = f2bf(v.w);
    }
    __syncthreads();
#pragma unroll
    for (int it = 0; it < 2; it++) {
        int x_l = it * 32 + (t >> 3);
        int ci_l = (t & 7) * 8;
        const unsigned int* p = (const unsigned int*)&tile[x_l * 66 + ci_l];
        uint4 u = make_uint4(p[0], p[1], p[2], p[3]);
        *(uint4*)&ctrlT[(((size_t)b * 128 + y) * 128 + x0 + x_l) * 128 + ci0 + ci_l] = u;
    }
}

// ---------------------------------------------------------------------------
// W-prep: w1 [50,128,9] -> w1p [c4=4][tap=9][co=64][ci=32] bf16 (pad co 50->64)
//         w2 [18,50,9]  -> w2p [c4=2][tap=9][co=32][ci=32] bf16 (pad both)
// ---------------------------------------------------------------------------
__global__ __launch_bounds__(256) void prep_w_kernel(
    const float* __restrict__ w1, const float* __restrict__ w2,
    unsigned short* __restrict__ w1p, unsigned short* __restrict__ w2p)
{
    int i = blockIdx.x * 256 + threadIdx.x;
    if (i < 4 * 9 * 64 * 32) {
        int ci = i & 31; int t2 = i >> 5; int co = t2 & 63; int t3 = t2 >> 6;
        int tap = t3 % 9; int c4 = t3 / 9;
        float v = 0.f;
        if (co < 50) v = w1[((size_t)co * 128 + c4 * 32 + ci) * 9 + tap];
        w1p[i] = f2bf(v);
    } else {
        int j = i - 4 * 9 * 64 * 32;
        int ci = j & 31; int t2 = j >> 5; int co = t2 & 31; int t3 = t2 >> 5;
        int tap = t3 % 9; int c4 = t3 / 9;
        int cig = c4 * 32 + ci;
        float v = 0.f;
        if (co < 18 && cig < 50) v = w2[((size_t)co * 50 + cig) * 9 + tap];
        w2p[j] = f2bf(v);
    }
}

// ---------------------------------------------------------------------------
// conv1 MFMA: ctrlT NHWC bf16 -> h NHWC bf16 [8,128,128,64] (bias+ReLU+BN fused)
// block 256 (4 waves). M-tile = 128 px (8 rows x 16 cols), N = 64 co.
// K = 4 ci-chunks x 9 taps x 32. Wave: 2 m-tiles x 4 n-tiles.
// ---------------------------------------------------------------------------
__global__ __launch_bounds__(256) void conv1_mfma(
    const unsigned short* __restrict__ xT, const unsigned short* __restrict__ w1p,
    const float* __restrict__ b1, const float* __restrict__ gamma,
    const float* __restrict__ beta, const float* __restrict__ mean,
    const float* __restrict__ var, unsigned short* __restrict__ h)
{
    __shared__ unsigned short in_s[180 * 40];     // 10x18 px, 32 ci (pad 40)
    __shared__ unsigned short w_s[9 * 64 * 40];   // tap x co x 32 ci (pad 40)
    const int tid = threadIdx.x;
    const int x0 = blockIdx.x * 16, y0 = blockIdx.y * 8, b = blockIdx.z;
    const int wid = tid >> 6, lane = tid & 63;
    const int ln = lane & 15, q = lane >> 4;

    floatx4 acc[2][4];
#pragma unroll
    for (int mt = 0; mt < 2; mt++)
#pragma unroll
        for (int nt = 0; nt < 4; nt++) acc[mt][nt] = (floatx4)(0.f);

    for (int c4 = 0; c4 < 4; c4++) {
        // stage input chunk: 180 px x 32 ci
#pragma unroll
        for (int it = 0; it < 3; it++) {
            int p = it * 64 + (tid >> 2);
            if (p < 180) {
                int g = tid & 3;
                int gy = y0 + p / 18 - 1, gx = x0 + p % 18 - 1;
                uint4 v = make_uint4(0, 0, 0, 0);
                if (gy >= 0 && gy < 128 && gx >= 0 && gx < 128)
                    v = *(const uint4*)&xT[(((size_t)b * 128 + gy) * 128 + gx) * 128 + c4 * 32 + g * 8];
                *(uint4*)&in_s[p * 40 + g * 8] = v;
            }
        }
        // stage weight chunk: 9 taps x 64 co x 32 ci = 2304 uint4
#pragma unroll
        for (int it = 0; it < 9; it++) {
            int f = it * 256 + tid;
            int g = f & 3, co = (f >> 2) & 63, tap = f >> 8;
            uint4 v = *(const uint4*)&w1p[(((size_t)c4 * 9 + tap) * 64 + co) * 32 + g * 8];
            *(uint4*)&w_s[(tap * 64 + co) * 40 + g * 8] = v;
        }
        __syncthreads();

#pragma unroll
        for (int tap = 0; tap < 9; tap++) {
            const int dy = tap / 3, dx = tap % 3;
            const int py = wid * 2;
            short8 a0 = *(const short8*)&in_s[((py + dy) * 18 + ln + dx) * 40 + q * 8];
            short8 a1 = *(const short8*)&in_s[((py + 1 + dy) * 18 + ln + dx) * 40 + q * 8];
#pragma unroll
            for (int nt = 0; nt < 4; nt++) {
                short8 bf = *(const short8*)&w_s[(tap * 64 + nt * 16 + ln) * 40 + q * 8];
                acc[0][nt] = __builtin_amdgcn_mfma_f32_16x16x32_bf16(a0, bf, acc[0][nt], 0, 0, 0);
                acc[1][nt] = __builtin_amdgcn_mfma_f32_16x16x32_bf16(a1, bf, acc[1][nt], 0, 0, 0);
            }
        }
        __syncthreads();
    }

    // epilogue: bias+ReLU+BN; co>=50 forced to 0 (padded channels of h)
#pragma unroll
    for (int nt = 0; nt < 4; nt++) {
        int co = nt * 16 + ln;
        bool real = co < 50;
        float sc = 0.f, mn = 0.f, bt = 0.f, bs = 0.f;
        if (real) {
            sc = gamma[co] * rsqrtf(var[co] + 1e-5f);
            mn = mean[co]; bt = beta[co]; bs = b1[co];
        }
#pragma unroll
        for (int mt = 0; mt < 2; mt++) {
            int py = wid * 2 + mt;
#pragma unroll
            for (int r = 0; r < 4; r++) {
                int px = q * 4 + r;
                float v = 0.f;
                if (real) {
                    float tv = fmaxf(acc[mt][nt][r] + bs, 0.f);
                    v = (tv - mn) * sc + bt;
                }
                h[(((size_t)b * 128 + y0 + py) * 128 + x0 + px) * 64 + co] = f2bf(v);
            }
        }
    }
}

// ---------------------------------------------------------------------------
// conv2 MFMA: h NHWC bf16 [..,64] -> cond NHWC f32 [8,128,128,18] (+bias)
// same template; K = 2 chunks x 9 taps, N = 32 (18 real). Wave: 2 mt x 2 nt.
// ---------------------------------------------------------------------------
__global__ __launch_bounds__(256) void conv2_mfma(
    const unsigned short* __restrict__ hT, const unsigned short* __restrict__ w2p,
    const float* __restrict__ b2, float* __restrict__ cond)
{
    __shared__ unsigned short in_s[180 * 40];
    __shared__ unsigned short w_s[9 * 32 * 40];
    const int tid = threadIdx.x;
    const int x0 = blockIdx.x * 16, y0 = blockIdx.y * 8, b = blockIdx.z;
    const int wid = tid >> 6, lane = tid & 63;
    const int ln = lane & 15, q = lane >> 4;

    floatx4 acc[2][2];
#pragma unroll
    for (int mt = 0; mt < 2; mt++)
#pragma unroll
        for (int nt = 0; nt < 2; nt++) acc[mt][nt] = (floatx4)(0.f);

    for (int c4 = 0; c4 < 2; c4++) {
#pragma unroll
        for (int it = 0; it < 3; it++) {
            int p = it * 64 + (tid >> 2);
            if (p < 180) {
                int g = tid & 3;
                int gy = y0 + p / 18 - 1, gx = x0 + p % 18 - 1;
                uint4 v = make_uint4(0, 0, 0, 0);
                if (gy >= 0 && gy < 128 && gx >= 0 && gx < 128)
                    v = *(const uint4*)&hT[(((size_t)b * 128 + gy) * 128 + gx) * 64 + c4 * 32 + g * 8];
                *(uint4*)&in_s[p * 40 + g * 8] = v;
            }
        }
#pragma unroll
        for (int it = 0; it < 5; it++) {
            int f = it * 256 + tid;   // < 9*32*4 = 1152
            if (f < 1152) {
                int g = f & 3, co = (f >> 2) & 31, tap = f >> 7;
                uint4 v = *(const uint4*)&w2p[(((size_t)c4 * 9 + tap) * 32 + co) * 32 + g * 8];
                *(uint4*)&w_s[(tap * 32 + co) * 40 + g * 8] = v;
            }
        }
        __syncthreads();

#pragma unroll
        for (int tap = 0; tap < 9; tap++) {
            const int dy = tap / 3, dx = tap % 3;
            const int py = wid * 2;
            short8 a0 = *(const short8*)&in_s[((py + dy) * 18 + ln + dx) * 40 + q * 8];
            short8 a1 = *(const short8*)&in_s[((py + 1 + dy) * 18 + ln + dx) * 40 + q * 8];
#pragma unroll
            for (int nt = 0; nt < 2; nt++) {
                short8 bf = *(const short8*)&w_s[(tap * 32 + nt * 16 + ln) * 40 + q * 8];
                acc[0][nt] = __builtin_amdgcn_mfma_f32_16x16x32_bf16(a0, bf, acc[0][nt], 0, 0, 0);
                acc[1][nt] = __builtin_amdgcn_mfma_f32_16x16x32_bf16(a1, bf, acc[1][nt], 0, 0, 0);
            }
        }
        __syncthreads();
    }

#pragma unroll
    for (int nt = 0; nt < 2; nt++) {
        int co = nt * 16 + ln;
        if (co < 18) {
            float bs = b2[co];
#pragma unroll
            for (int mt = 0; mt < 2; mt++) {
                int py = wid * 2 + mt;
#pragma unroll
                for (int r = 0; r < 4; r++) {
                    int px = q * 4 + r;
                    cond[(((size_t)b * 128 + y0 + py) * 128 + x0 + px) * 18 + co] = acc[mt][nt][r] + bs;
                }
            }
        }
    }
}

// ---------------------------------------------------------------------------
// apply: out[b,c,y,x] = sum_k img[b,c,y+(k%3)*4-4, x+(k/3)*4-4] * cond[b,cy,cx,(c/3)*9+k]
// ---------------------------------------------------------------------------
__global__ __launch_bounds__(256) void apply_kernel(
    const float* __restrict__ img, const float* __restrict__ cond,
    float* __restrict__ out)
{
    const int t = blockIdx.x * 256 + threadIdx.x;
    const int x4 = t & 127;         // x/4 == cell x
    const int y = (t >> 7) & 511;
    const int b = t >> 16;
    const int cy = y >> 2;

    float w[2][9];
    const float* cw = &cond[(((size_t)b * 128 + cy) * 128 + x4) * 18];
#pragma unroll
    for (int g = 0; g < 2; g++)
#pragma unroll
        for (int k = 0; k < 9; k++)
            w[g][k] = cw[g * 9 + k];

#pragma unroll
    for (int c = 0; c < 6; c++) {
        const int g = c / 3;
        float4 acc = make_float4(0.f, 0.f, 0.f, 0.f);
#pragma unroll
        for (int i = 0; i < 3; i++) {
            int xx = x4 * 4 + i * 4 - 4;
            if (xx < 0 || xx >= 512) continue;
#pragma unroll
            for (int j = 0; j < 3; j++) {
                int yy = y + j * 4 - 4;
                if (yy < 0 || yy >= 512) continue;
                const float4 v = *(const float4*)&img[(((size_t)b * 6 + c) * 512 + yy) * 512 + xx];
                float wv = w[g][i * 3 + j];
                acc.x += v.x * wv;
                acc.y += v.y * wv;
                acc.z += v.z * wv;
                acc.w += v.w * wv;
            }
        }
        *(float4*)&out[(((size_t)b * 6 + c) * 512 + y) * 512 + x4 * 4] = acc;
    }
}

// ---------------------------------------------------------------------------
extern "C" void kernel_launch(void* const* d_in, const int* in_sizes, int n_in,
                              void* d_out, int out_size, void* d_ws, size_t ws_size,
                              hipStream_t stream)
{
    const float* img   = (const float*)d_in[0];
    const float* ctrl  = (const float*)d_in[1];
    const float* w1    = (const float*)d_in[2];
    const float* b1    = (const float*)d_in[3];
    const float* gamma = (const float*)d_in[4];
    const float* beta  = (const float*)d_in[5];
    const float* mean  = (const float*)d_in[6];
    const float* var   = (const float*)d_in[7];
    const float* w2    = (const float*)d_in[8];
    const float* b2    = (const float*)d_in[9];
    float* out = (float*)d_out;

    char* ws = (char*)d_ws;
    unsigned short* ctrlT = (unsigned short*)ws;                        // 33,554,432 B
    unsigned short* hbuf  = (unsigned short*)(ws + 33554432);           // 16,777,216 B
    float*          cond  = (float*)(ws + 50331648);                    //  9,437,184 B
    unsigned short* w1p   = (unsigned short*)(ws + 59768832);           //    147,456 B
    unsigned short* w2p   = (unsigned short*)(ws + 59916288);           //     36,864 B

    transpose_kernel<<<dim3(2, 2, 1024), 256, 0, stream>>>(ctrl, ctrlT);
    prep_w_kernel<<<360, 256, 0, stream>>>(w1, w2, w1p, w2p);
    conv1_mfma<<<dim3(8, 16, 8), 256, 0, stream>>>(ctrlT, w1p, b1, gamma, beta, mean, var, hbuf);
    conv2_mfma<<<dim3(8, 16, 8), 256, 0, stream>>>(hbuf, w2p, b2, cond);
    apply_kernel<<<2048, 256, 0, stream>>>(img, cond, out);
}

// Round 3
// 221.197 us; speedup vs baseline: 3.4954x; 1.2158x over previous
//
#include <hip/hip_runtime.h>

typedef __attribute__((ext_vector_type(8))) short short8;
typedef __attribute__((ext_vector_type(4))) float floatx4;

__device__ __forceinline__ unsigned short f2bf(float f) {
    union { float f; unsigned int u; } v; v.f = f;
    unsigned int r = (v.u + 0x7fffu + ((v.u >> 16) & 1u)) >> 16;
    return (unsigned short)r;
}

// ---------------------------------------------------------------------------
// T: ctrl [8,128,128,128] f32 NCHW -> ctrlT [8,128y,128x,128ci] bf16 NHWC
// ---------------------------------------------------------------------------
__global__ __launch_bounds__(256) void transpose_kernel(
    const float* __restrict__ ctrl, unsigned short* __restrict__ ctrlT)
{
    __shared__ unsigned short tile[64 * 66];
    const int t = threadIdx.x;
    const int x0 = blockIdx.x * 64, ci0 = blockIdx.y * 64;
    const int b = blockIdx.z >> 7, y = blockIdx.z & 127;
#pragma unroll
    for (int it = 0; it < 4; it++) {
        int ci_l = it * 16 + (t >> 4);
        int x_l = (t & 15) * 4;
        const float4 v = *(const float4*)&ctrl[(((size_t)b * 128 + ci0 + ci_l) * 128 + y) * 128 + x0 + x_l];
        tile[(x_l + 0) * 66 + ci_l] = f2bf(v.x);
        tile[(x_l + 1) * 66 + ci_l] = f2bf(v.y);
        tile[(x_l + 2) * 66 + ci_l] = f2bf(v.z);
        tile[(x_l + 3) * 66 + ci_l] = f2bf(v.w);
    }
    __syncthreads();
#pragma unroll
    for (int it = 0; it < 2; it++) {
        int x_l = it * 32 + (t >> 3);
        int ci_l = (t & 7) * 8;
        const unsigned int* p = (const unsigned int*)&tile[x_l * 66 + ci_l];
        uint4 u = make_uint4(p[0], p[1], p[2], p[3]);
        *(uint4*)&ctrlT[(((size_t)b * 128 + y) * 128 + x0 + x_l) * 128 + ci0 + ci_l] = u;
    }
}

// ---------------------------------------------------------------------------
// W-prep: w1 -> [c4=4][tap=9][co=64][ci=32] bf16 ; w2 -> [c4=2][tap=9][co=32][ci=32]
// ---------------------------------------------------------------------------
__global__ __launch_bounds__(256) void prep_w_kernel(
    const float* __restrict__ w1, const float* __restrict__ w2,
    unsigned short* __restrict__ w1p, unsigned short* __restrict__ w2p)
{
    int i = blockIdx.x * 256 + threadIdx.x;
    if (i < 4 * 9 * 64 * 32) {
        int ci = i & 31; int t2 = i >> 5; int co = t2 & 63; int t3 = t2 >> 6;
        int tap = t3 % 9; int c4 = t3 / 9;
        float v = 0.f;
        if (co < 50) v = w1[((size_t)co * 128 + c4 * 32 + ci) * 9 + tap];
        w1p[i] = f2bf(v);
    } else {
        int j = i - 4 * 9 * 64 * 32;
        int ci = j & 31; int t2 = j >> 5; int co = t2 & 31; int t3 = t2 >> 5;
        int tap = t3 % 9; int c4 = t3 / 9;
        int cig = c4 * 32 + ci;
        float v = 0.f;
        if (co < 18 && cig < 50) v = w2[((size_t)co * 50 + cig) * 9 + tap];
        w2p[j] = f2bf(v);
    }
}

// ---------------------------------------------------------------------------
// conv1 MFMA: M-tile 256 px (16x16), N = 64 co. Wave: 4 mt x 4 nt.
// grid (8,8,8); LDS 72 KB -> 2 blocks/CU.
// ---------------------------------------------------------------------------
__global__ __launch_bounds__(256) void conv1_mfma(
    const unsigned short* __restrict__ xT, const unsigned short* __restrict__ w1p,
    const float* __restrict__ b1, const float* __restrict__ gamma,
    const float* __restrict__ beta, const float* __restrict__ mean,
    const float* __restrict__ var, unsigned short* __restrict__ h)
{
    __shared__ unsigned short in_s[324 * 40];     // 18x18 px halo, 32 ci (pad 40)
    __shared__ unsigned short w_s[9 * 64 * 40];   // tap x co x 32 ci
    const int tid = threadIdx.x;
    const int x0 = blockIdx.x * 16, y0 = blockIdx.y * 16, b = blockIdx.z;
    const int wid = tid >> 6, lane = tid & 63;
    const int ln = lane & 15, q = lane >> 4;

    floatx4 acc[4][4];
#pragma unroll
    for (int mt = 0; mt < 4; mt++)
#pragma unroll
        for (int nt = 0; nt < 4; nt++) acc[mt][nt] = (floatx4)(0.f);

    for (int c4 = 0; c4 < 4; c4++) {
        // stage input: 324 px x 32 ci = 1296 uint4
        for (int i = tid; i < 1296; i += 256) {
            int p = i >> 2, g = i & 3;
            int gy = y0 + p / 18 - 1, gx = x0 + p % 18 - 1;
            uint4 v = make_uint4(0, 0, 0, 0);
            if (gy >= 0 && gy < 128 && gx >= 0 && gx < 128)
                v = *(const uint4*)&xT[(((size_t)b * 128 + gy) * 128 + gx) * 128 + c4 * 32 + g * 8];
            *(uint4*)&in_s[p * 40 + g * 8] = v;
        }
        // stage weights: 2304 uint4
#pragma unroll
        for (int it = 0; it < 9; it++) {
            int f = it * 256 + tid;
            int g = f & 3, co = (f >> 2) & 63, tap = f >> 8;
            uint4 v = *(const uint4*)&w1p[(((size_t)c4 * 9 + tap) * 64 + co) * 32 + g * 8];
            *(uint4*)&w_s[(tap * 64 + co) * 40 + g * 8] = v;
        }
        __syncthreads();

#pragma unroll
        for (int tap = 0; tap < 9; tap++) {
            const int dy = tap / 3, dx = tap % 3;
            short8 a[4];
#pragma unroll
            for (int mt = 0; mt < 4; mt++)
                a[mt] = *(const short8*)&in_s[((wid * 4 + mt + dy) * 18 + ln + dx) * 40 + q * 8];
#pragma unroll
            for (int nt = 0; nt < 4; nt++) {
                short8 bf = *(const short8*)&w_s[(tap * 64 + nt * 16 + ln) * 40 + q * 8];
#pragma unroll
                for (int mt = 0; mt < 4; mt++)
                    acc[mt][nt] = __builtin_amdgcn_mfma_f32_16x16x32_bf16(a[mt], bf, acc[mt][nt], 0, 0, 0);
            }
        }
        __syncthreads();
    }

#pragma unroll
    for (int nt = 0; nt < 4; nt++) {
        int co = nt * 16 + ln;
        bool real = co < 50;
        float sc = 0.f, mn = 0.f, bt = 0.f, bs = 0.f;
        if (real) {
            sc = gamma[co] * rsqrtf(var[co] + 1e-5f);
            mn = mean[co]; bt = beta[co]; bs = b1[co];
        }
#pragma unroll
        for (int mt = 0; mt < 4; mt++) {
            int gy = y0 + wid * 4 + mt;
#pragma unroll
            for (int r = 0; r < 4; r++) {
                int px = q * 4 + r;
                float v = 0.f;
                if (real) {
                    float tv = fmaxf(acc[mt][nt][r] + bs, 0.f);
                    v = (tv - mn) * sc + bt;
                }
                h[(((size_t)b * 128 + gy) * 128 + x0 + px) * 64 + co] = f2bf(v);
            }
        }
    }
}

// ---------------------------------------------------------------------------
// conv2 MFMA: M-tile 256 px, N = 32 (18 real). Wave: 4 mt x 2 nt. grid (8,8,8)
// ---------------------------------------------------------------------------
__global__ __launch_bounds__(256) void conv2_mfma(
    const unsigned short* __restrict__ hT, const unsigned short* __restrict__ w2p,
    const float* __restrict__ b2, float* __restrict__ cond)
{
    __shared__ unsigned short in_s[324 * 40];
    __shared__ unsigned short w_s[9 * 32 * 40];
    const int tid = threadIdx.x;
    const int x0 = blockIdx.x * 16, y0 = blockIdx.y * 16, b = blockIdx.z;
    const int wid = tid >> 6, lane = tid & 63;
    const int ln = lane & 15, q = lane >> 4;

    floatx4 acc[4][2];
#pragma unroll
    for (int mt = 0; mt < 4; mt++)
#pragma unroll
        for (int nt = 0; nt < 2; nt++) acc[mt][nt] = (floatx4)(0.f);

    for (int c4 = 0; c4 < 2; c4++) {
        for (int i = tid; i < 1296; i += 256) {
            int p = i >> 2, g = i & 3;
            int gy = y0 + p / 18 - 1, gx = x0 + p % 18 - 1;
            uint4 v = make_uint4(0, 0, 0, 0);
            if (gy >= 0 && gy < 128 && gx >= 0 && gx < 128)
                v = *(const uint4*)&hT[(((size_t)b * 128 + gy) * 128 + gx) * 64 + c4 * 32 + g * 8];
            *(uint4*)&in_s[p * 40 + g * 8] = v;
        }
#pragma unroll
        for (int it = 0; it < 5; it++) {
            int f = it * 256 + tid;
            if (f < 1152) {
                int g = f & 3, co = (f >> 2) & 31, tap = f >> 7;
                uint4 v = *(const uint4*)&w2p[(((size_t)c4 * 9 + tap) * 32 + co) * 32 + g * 8];
                *(uint4*)&w_s[(tap * 32 + co) * 40 + g * 8] = v;
            }
        }
        __syncthreads();

#pragma unroll
        for (int tap = 0; tap < 9; tap++) {
            const int dy = tap / 3, dx = tap % 3;
            short8 a[4];
#pragma unroll
            for (int mt = 0; mt < 4; mt++)
                a[mt] = *(const short8*)&in_s[((wid * 4 + mt + dy) * 18 + ln + dx) * 40 + q * 8];
#pragma unroll
            for (int nt = 0; nt < 2; nt++) {
                short8 bf = *(const short8*)&w_s[(tap * 32 + nt * 16 + ln) * 40 + q * 8];
#pragma unroll
                for (int mt = 0; mt < 4; mt++)
                    acc[mt][nt] = __builtin_amdgcn_mfma_f32_16x16x32_bf16(a[mt], bf, acc[mt][nt], 0, 0, 0);
            }
        }
        __syncthreads();
    }

#pragma unroll
    for (int nt = 0; nt < 2; nt++) {
        int co = nt * 16 + ln;
        if (co < 18) {
            float bs = b2[co];
#pragma unroll
            for (int mt = 0; mt < 4; mt++) {
                int gy = y0 + wid * 4 + mt;
#pragma unroll
                for (int r = 0; r < 4; r++) {
                    int px = q * 4 + r;
                    cond[(((size_t)b * 128 + gy) * 128 + x0 + px) * 18 + co] = acc[mt][nt][r] + bs;
                }
            }
        }
    }
}

// ---------------------------------------------------------------------------
// apply: rolling y-strip. Thread = (x4 column, sub-row s); strip = 32 rows.
// Out rows o_j = base + 4j + s (j=0..7). Row loads r_m = base + s + 4(m-1),
// m=0..9 -> 10 loads / 8 outputs (1.25x). 3-slot rolling accumulator.
// grid (2, 16, 8); block 256 = 64 x4 cols x 4 s.
// ---------------------------------------------------------------------------
__global__ __launch_bounds__(256) void apply_kernel(
    const float* __restrict__ img, const float* __restrict__ cond,
    float* __restrict__ out)
{
    const int tid = threadIdx.x;
    const int xl = tid & 63, s = tid >> 6;
    const int x4 = blockIdx.x * 64 + xl;
    const int base = blockIdx.y * 32;
    const int b = blockIdx.z;
    const int cyb = base >> 2;

    float4 acc[3][6];
#pragma unroll
    for (int sl = 0; sl < 3; sl++)
#pragma unroll
        for (int c = 0; c < 6; c++) acc[sl][c] = make_float4(0.f, 0.f, 0.f, 0.f);

#pragma unroll
    for (int m = 0; m <= 9; m++) {
        const int r = base + s + 4 * (m - 1);
        const bool rok = (r >= 0) && (r < 512);   // wave-uniform (s = wave id)
        float4 v[6][3];
#pragma unroll
        for (int c = 0; c < 6; c++)
#pragma unroll
            for (int i = 0; i < 3; i++) {
                int xx = x4 * 4 + i * 4 - 4;
                v[c][i] = make_float4(0.f, 0.f, 0.f, 0.f);
                if (rok && xx >= 0 && xx < 512)
                    v[c][i] = *(const float4*)&img[(((size_t)b * 6 + c) * 512 + r) * 512 + xx];
            }
#pragma unroll
        for (int j = m - 2; j <= m; j++) {
            if (j >= 0 && j < 8) {
                const int jy = m - j;
                const int slot = j % 3;
                const float* cw = &cond[(((size_t)b * 128 + cyb + j) * 128 + x4) * 18];
#pragma unroll
                for (int g = 0; g < 2; g++)
#pragma unroll
                    for (int i = 0; i < 3; i++) {
                        float wv = cw[g * 9 + i * 3 + jy];
#pragma unroll
                        for (int cc = 0; cc < 3; cc++) {
                            int c = g * 3 + cc;
                            acc[slot][c].x += v[c][i].x * wv;
                            acc[slot][c].y += v[c][i].y * wv;
                            acc[slot][c].z += v[c][i].z * wv;
                            acc[slot][c].w += v[c][i].w * wv;
                        }
                    }
            }
        }
        const int jd = m - 2;
        if (jd >= 0 && jd < 8) {
            const int o = base + 4 * jd + s;
            const int slot = jd % 3;
#pragma unroll
            for (int c = 0; c < 6; c++) {
                *(float4*)&out[(((size_t)b * 6 + c) * 512 + o) * 512 + x4 * 4] = acc[slot][c];
                acc[slot][c] = make_float4(0.f, 0.f, 0.f, 0.f);
            }
        }
    }
}

// ---------------------------------------------------------------------------
extern "C" void kernel_launch(void* const* d_in, const int* in_sizes, int n_in,
                              void* d_out, int out_size, void* d_ws, size_t ws_size,
                              hipStream_t stream)
{
    const float* img   = (const float*)d_in[0];
    const float* ctrl  = (const float*)d_in[1];
    const float* w1    = (const float*)d_in[2];
    const float* b1    = (const float*)d_in[3];
    const float* gamma = (const float*)d_in[4];
    const float* beta  = (const float*)d_in[5];
    const float* mean  = (const float*)d_in[6];
    const float* var   = (const float*)d_in[7];
    const float* w2    = (const float*)d_in[8];
    const float* b2    = (const float*)d_in[9];
    float* out = (float*)d_out;

    char* ws = (char*)d_ws;
    unsigned short* ctrlT = (unsigned short*)ws;                        // 33,554,432 B
    unsigned short* hbuf  = (unsigned short*)(ws + 33554432);           // 16,777,216 B
    float*          cond  = (float*)(ws + 50331648);                    //  9,437,184 B
    unsigned short* w1p   = (unsigned short*)(ws + 59768832);           //    147,456 B
    unsigned short* w2p   = (unsigned short*)(ws + 59916288);           //     36,864 B

    transpose_kernel<<<dim3(2, 2, 1024), 256, 0, stream>>>(ctrl, ctrlT);
    prep_w_kernel<<<360, 256, 0, stream>>>(w1, w2, w1p, w2p);
    conv1_mfma<<<dim3(8, 8, 8), 256, 0, stream>>>(ctrlT, w1p, b1, gamma, beta, mean, var, hbuf);
    conv2_mfma<<<dim3(8, 8, 8), 256, 0, stream>>>(hbuf, w2p, b2, cond);
    apply_kernel<<<dim3(2, 16, 8), 256, 0, stream>>>(img, cond, out);
}